// Round 4
// baseline (508.796 us; speedup 1.0000x reference)
//
#include <hip/hip_runtime.h>
#include <cstdint>
#include <cstddef>

typedef unsigned short u16;
typedef __attribute__((ext_vector_type(8))) short bf16x8;   // 8 bf16 = 4 VGPRs
typedef __attribute__((ext_vector_type(4))) float f32x4;    // MFMA 16x16 accum

#define NB    64    // batch
#define NTOK  625   // tokens (25x25)
#define NTOKP 640   // padded tokens
#define DDIM  512
#define NH    8
#define DH    64

__device__ __forceinline__ float bf2f(u16 v) {
    return __uint_as_float(((unsigned int)v) << 16);
}
__device__ __forceinline__ u16 f2bf(float f) {           // RNE
    unsigned int x = __float_as_uint(f);
    unsigned int r = (x + 0x7fffu + ((x >> 16) & 1u)) >> 16;
    return (u16)r;
}
__device__ __forceinline__ u16 f2bf_fast(float f) {      // round-half-up (2 ops)
    return (u16)((__float_as_uint(f) + 0x8000u) >> 16);
}

// async global->LDS, 16B per lane (m97 pattern); fallback = sync staging
#if __has_builtin(__builtin_amdgcn_global_load_lds)
typedef const __attribute__((address_space(1))) void gas_void;
typedef __attribute__((address_space(3))) void las_void;
__device__ __forceinline__ void glds16(const void* g, void* l) {
    __builtin_amdgcn_global_load_lds((gas_void*)g, (las_void*)l, 16, 0, 0);
}
#else
__device__ __forceinline__ void glds16(const void* g, void* l) {
    *(uint4*)l = *(const uint4*)g;
}
#endif

// ---------------- transpose x: f32 (b, d, n) -> bf16 tokens (b, n, d) ----------------
__global__ __launch_bounds__(256) void k_transpose_x(const float* __restrict__ x,
                                                     u16* __restrict__ tokens) {
    __shared__ u16 T[64][66];
    int b = blockIdx.z, ct = blockIdx.y, it = blockIdx.x;
    int t = threadIdx.x;
    int i0 = it * 64, c0 = ct * 64;
#pragma unroll
    for (int r = 0; r < 2; r++) {
        int c = (t >> 3) + r * 32;
        int i8 = (t & 7) * 8;
        const float* s = x + ((size_t)b * DDIM + c0 + c) * NTOK + i0 + i8;
#pragma unroll
        for (int u = 0; u < 8; u++)
            T[c][i8 + u] = (i0 + i8 + u < NTOK) ? f2bf(s[u]) : (u16)0;
    }
    __syncthreads();
#pragma unroll
    for (int r = 0; r < 2; r++) {
        int i = (t >> 3) + r * 32;
        int c8 = (t & 7) * 8;
        int gi = i0 + i;
        if (gi < NTOK) {
            u16* d = tokens + ((size_t)b * NTOK + gi) * DDIM + c0 + c8;
#pragma unroll
            for (int u = 0; u < 8; u++) d[u] = T[c8 + u][i];
        }
    }
}

// ---------------- weight transpose: f32 src[R][C] -> bf16 dst[C][R] ----------------
__global__ __launch_bounds__(256) void k_transpose_w(const float* __restrict__ src,
                                                     u16* __restrict__ dst, int R, int C) {
    __shared__ u16 T[64][66];
    int r0 = blockIdx.y * 64, c0 = blockIdx.x * 64;
    int t = threadIdx.x;
#pragma unroll
    for (int rr = 0; rr < 2; rr++) {
        int r = (t >> 3) + rr * 32;
        int c8 = (t & 7) * 8;
        const float* s = src + (size_t)(r0 + r) * C + c0 + c8;
#pragma unroll
        for (int u = 0; u < 8; u++) T[r][c8 + u] = f2bf(s[u]);
    }
    __syncthreads();
#pragma unroll
    for (int rr = 0; rr < 2; rr++) {
        int c = (t >> 3) + rr * 32;
        int r8 = (t & 7) * 8;
        u16* d = dst + (size_t)(c0 + c) * R + r0 + r8;
#pragma unroll
        for (int u = 0; u < 8; u++) d[u] = T[r8 + u][c];
    }
}

// ---------------- bias expand into MFMA C-layout (f32), masking folded in ----------
// biasCf[((m*10+jt)*10+it)*4096 + t*16 + jj*4 + r]; thread t of the attn block.
__global__ __launch_bounds__(256) void k_bias(const int* __restrict__ rpi,
                                              const float* __restrict__ rpb,
                                              float* __restrict__ biasCf) {
    int blk = blockIdx.x;               // 800 = m*100 + jt*10 + it
    int m = blk / 100, jt = (blk / 10) % 10, it = blk % 10;
    int t = threadIdx.x;
    float vals[16];
#pragma unroll
    for (int jj = 0; jj < 4; jj++) {
        int gj = jt * 64 + jj * 16 + (t & 15);
#pragma unroll
        for (int r = 0; r < 4; r++) {
            int gi = it * 64 + (t >> 6) * 16 + ((t >> 4) & 3) * 4 + r;
            float v;
            if (gj >= NTOK) v = -1e30f;
            else if (gi >= NTOK) v = 0.f;
            else v = rpb[rpi[gi * NTOK + gj] * NH + m];
            vals[jj * 4 + r] = v;
        }
    }
    float* d = biasCf + ((size_t)(m * 10 + jt) * 10 + it) * 4096 + t * 16;
#pragma unroll
    for (int g = 0; g < 4; g++)
        *(f32x4*)(d + g * 4) = *(f32x4*)&vals[g * 4];
}

// ---------------- QKV GEMM: BK=64, XCD-swizzled, bank-swizzled LDS ------------------
// q (scaled 0.125) -> qk[b][i][0..511]; k -> qk[b][i][512..1023];
// v -> vT[b][hd][tc][n'] with n' = tile*64 + pi(tok), pi(v) = (v&15)*4 + (v>>4).
__global__ __launch_bounds__(256) void k_qkv(const u16* __restrict__ tokens,
                                             const u16* __restrict__ wT,
                                             u16* __restrict__ qk, u16* __restrict__ vT) {
    __shared__ u16 SMEM[16384];         // As [128][64] | Bs [128][64]; reused in epilogue
    // XCD swizzle: co-locate the 12 jt-blocks sharing one A-slab on one XCD
    int bid = blockIdx.x;               // 3840 blocks
    int c8id = bid & 7, t2 = bid >> 3;  // t2 in [0,480)
    int jt = t2 % 12, q_ = t2 / 12;     // q_ in [0,40)
    int itb = q_ * 8 + c8id;            // [0,320)
    int it = itb % 5, b = itb / 5;
    int i0 = it * 128, j0 = jt * 128;
    int t = threadIdx.x;
    int w = t >> 6, lane = t & 63, quad = lane >> 4, l15 = lane & 15;
    int wr = w >> 1, wc = w & 1;
    f32x4 acc[4][4] = {};
    const u16* abase = tokens + ((size_t)b * NTOK + i0) * DDIM;
    const u16* bbase = wT + (size_t)j0 * DDIM;
    for (int k0 = 0; k0 < DDIM; k0 += 64) {
        __syncthreads();
#pragma unroll
        for (int c = 0; c < 4; c++) {
            int unit = c * 256 + t;
            int row = unit >> 3, cc = unit & 7;
            int gcol = (cc ^ (row & 7)) * 8;            // bank swizzle via global src
            glds16(abase + (size_t)row * DDIM + k0 + gcol, SMEM + unit * 8);
            glds16(bbase + (size_t)row * DDIM + k0 + gcol, SMEM + 8192 + unit * 8);
        }
        __syncthreads();
#pragma unroll
        for (int kk = 0; kk < 2; kk++) {
            bf16x8 af[4], bfv[4];
            int chA = (((kk * 4 + quad) ^ (l15 & 7))) * 8;
#pragma unroll
            for (int q2 = 0; q2 < 4; q2++) {
                af[q2]  = *(const bf16x8*)&SMEM[(wr * 64 + q2 * 16 + l15) * 64 + chA];
                bfv[q2] = *(const bf16x8*)&SMEM[8192 + (wc * 64 + q2 * 16 + l15) * 64 + chA];
            }
#pragma unroll
            for (int ii = 0; ii < 4; ii++)
#pragma unroll
                for (int jj = 0; jj < 4; jj++)
                    acc[ii][jj] = __builtin_amdgcn_mfma_f32_16x16x32_bf16(af[ii], bfv[jj], acc[ii][jj], 0, 0, 0);
        }
    }
    __syncthreads();                    // SMEM reuse
    if (jt < 8) {
        // q/k epilogue via T2[64][136]: rows=token half, cols=128 channels
        float scale = (j0 < 512) ? 0.125f : 1.0f;
#pragma unroll
        for (int h = 0; h < 2; h++) {
            if (h) __syncthreads();
            if (wr == h) {
#pragma unroll
                for (int ii = 0; ii < 4; ii++)
#pragma unroll
                    for (int jj = 0; jj < 4; jj++)
#pragma unroll
                        for (int r = 0; r < 4; r++)
                            SMEM[(ii * 16 + quad * 4 + r) * 136 + wc * 64 + jj * 16 + l15] =
                                f2bf(acc[ii][jj][r] * scale);
            }
            __syncthreads();
#pragma unroll
            for (int g = 0; g < 4; g++) {
                int unit = g * 256 + t;
                int tok = unit >> 4, ch8 = (unit & 15) * 8;
                int gi = i0 + h * 64 + tok;
                if (gi < NTOK)
                    *(uint4*)(qk + ((size_t)b * NTOK + gi) * 1024 + j0 + ch8) =
                        *(uint4*)&SMEM[tok * 136 + ch8];
            }
        }
    } else {
        // v epilogue via T[128][72]: rows=channel, cols=pi(token); zero pad-tokens
        int ch0 = j0 - 1024;
#pragma unroll
        for (int h = 0; h < 2; h++) {
            if (h) __syncthreads();
            if (wr == h) {
#pragma unroll
                for (int ii = 0; ii < 4; ii++)
#pragma unroll
                    for (int jj = 0; jj < 4; jj++)
#pragma unroll
                        for (int r = 0; r < 4; r++) {
                            int tok = ii * 16 + quad * 4 + r;       // within 64-half
                            int gi = i0 + h * 64 + tok;
                            u16 val = (gi < NTOK) ? f2bf(acc[ii][jj][r]) : (u16)0;
                            SMEM[(wc * 64 + jj * 16 + l15) * 72 + (tok & 15) * 4 + (tok >> 4)] = val;
                        }
            }
            __syncthreads();
#pragma unroll
            for (int g = 0; g < 4; g++) {
                int unit = g * 256 + t;
                int chl = unit >> 3, tok8 = (unit & 7) * 8;
                int chv = ch0 + chl, hd = chv >> 6, tc = chv & 63;
                *(uint4*)(vT + (((size_t)b * NH + hd) * DH + tc) * NTOKP + i0 + h * 64 + tok8) =
                    *(uint4*)&SMEM[chl * 72 + tok8];
            }
        }
    }
}

// ---------------- attention: XCD-swizzled, f32 bias init, ones-tile row sums --------
__global__ __launch_bounds__(256) void k_attn(const u16* __restrict__ qk,
                                              const u16* __restrict__ vT,
                                              const float* __restrict__ biasCf,
                                              u16* __restrict__ attnout) {
    __shared__ u16 Qs[64][72];
    __shared__ u16 Ks[64][72];
    __shared__ u16 Vs[80][72];          // rows 64..79 = 1.0 (row-sum ones tile)
    __shared__ u16 Ps[64][72];
    // XCD swizzle: co-locate the 10 i-tiles sharing one head's K/V on one XCD
    int bid = blockIdx.x;               // 5120 blocks
    int c8id = bid & 7, t2 = bid >> 3;  // t2 in [0,640)
    int it = t2 % 10, q_ = t2 / 10;     // q_ in [0,64)
    int bm = q_ * 8 + c8id;             // [0,512)
    int m = bm & 7, b = bm >> 3;
    int i0 = it * 64;
    int t = threadIdx.x;
    int w = t >> 6, lane = t & 63, quad = lane >> 4, l15 = lane & 15;
    {   // ones rows for the sum tile
        int row = 64 + (t >> 4), c4 = (t & 15) * 4;
        *(uint2*)&Vs[row][c4] = make_uint2(0x3F803F80u, 0x3F803F80u);
    }
#pragma unroll
    for (int r = 0; r < 2; r++) {       // Q tile (zero OOB rows)
        int row = (t >> 3) + r * 32;
        int t8 = (t & 7) * 8;
        int gi = i0 + row;
        uint4 v;
        if (gi < NTOK) v = *(const uint4*)(qk + ((size_t)b * NTOK + gi) * 1024 + m * DH + t8);
        else v = make_uint4(0, 0, 0, 0);
        *(uint4*)&Qs[row][t8] = v;
    }
    f32x4 oacc[5] = {};                 // [4] = row sums (ones tile)
    const u16* vbase = vT + ((size_t)b * NH + m) * DH * NTOKP;
    const float* bC = biasCf + (size_t)(m * 100 + it) * 4096 + t * 16;

    for (int jt = 0; jt < 10; jt++) {
        int j0 = jt * 64;
        __syncthreads();                // prior Ks/Vs reads done
#pragma unroll
        for (int r = 0; r < 2; r++) {   // stage K (rows=j) and V (rows=dh, pi-token cols)
            int row = (t >> 3) + r * 32;
            int c8 = (t & 7) * 8;
            int gj = j0 + row;
            uint4 kv;
            if (gj < NTOK) kv = *(const uint4*)(qk + ((size_t)b * NTOK + gj) * 1024 + 512 + m * DH + c8);
            else kv = make_uint4(0, 0, 0, 0);
            *(uint4*)&Ks[row][c8] = kv;
            uint4 vv = *(const uint4*)(vbase + (size_t)row * NTOKP + j0 + c8);
            *(uint4*)&Vs[row][c8] = vv;
        }
        __syncthreads();
        // S init = f32 C-layout bias (masking pre-folded), zero VALU
        const float* bp = bC + (size_t)jt * 10 * 4096;
        f32x4 s[4];
#pragma unroll
        for (int jj = 0; jj < 4; jj++) s[jj] = *(const f32x4*)(bp + jj * 4);
        bf16x8 aq[2];
#pragma unroll
        for (int kk = 0; kk < 2; kk++)
            aq[kk] = *(const bf16x8*)&Qs[w * 16 + l15][kk * 32 + quad * 8];
#pragma unroll
        for (int jj = 0; jj < 4; jj++)
#pragma unroll
            for (int kk = 0; kk < 2; kk++) {
                bf16x8 bk = *(const bf16x8*)&Ks[jj * 16 + l15][kk * 32 + quad * 8];
                s[jj] = __builtin_amdgcn_mfma_f32_16x16x32_bf16(aq[kk], bk, s[jj], 0, 0, 0);
            }
        // P = exp(S); constant shift cancels in normalization (bounded scores)
#pragma unroll
        for (int r = 0; r < 4; r++) {
            float p0 = __expf(s[0][r]), p1 = __expf(s[1][r]);
            float p2 = __expf(s[2][r]), p3 = __expf(s[3][r]);
            uint2 pk;
            pk.x = (unsigned)f2bf_fast(p0) | ((unsigned)f2bf_fast(p1) << 16);
            pk.y = (unsigned)f2bf_fast(p2) | ((unsigned)f2bf_fast(p3) << 16);
            // pi-packed P row: col = l15*4 + jj  (matches vT token order)
            *(uint2*)&Ps[w * 16 + quad * 4 + r][l15 * 4] = pk;
        }
        // same-wave rows only -> no barrier needed before re-read
        bf16x8 ap[2];
#pragma unroll
        for (int kk = 0; kk < 2; kk++)
            ap[kk] = *(const bf16x8*)&Ps[w * 16 + l15][kk * 32 + quad * 8];
#pragma unroll
        for (int tt = 0; tt < 5; tt++)
#pragma unroll
            for (int kk = 0; kk < 2; kk++) {
                bf16x8 bv = *(const bf16x8*)&Vs[tt * 16 + l15][kk * 32 + quad * 8];
                oacc[tt] = __builtin_amdgcn_mfma_f32_16x16x32_bf16(ap[kk], bv, oacc[tt], 0, 0, 0);
            }
    }
    float rinv[4];
#pragma unroll
    for (int r = 0; r < 4; r++) rinv[r] = __frcp_rn(oacc[4][r]);
#pragma unroll
    for (int tt = 0; tt < 4; tt++)
#pragma unroll
        for (int r = 0; r < 4; r++) {
            int gi = i0 + w * 16 + quad * 4 + r;
            if (gi < NTOK)
                attnout[((size_t)b * NTOK + gi) * DDIM + m * DH + tt * 16 + l15] =
                    f2bf(oacc[tt][r] * rinv[r]);
        }
}

// ---------------- out GEMM (C^T): BK=64, XCD-swizzled ------------------------------
__global__ __launch_bounds__(256) void k_out(const u16* __restrict__ attnout,
                                             const u16* __restrict__ woT,
                                             float* __restrict__ out) {
    __shared__ u16 SMEM[16384];         // As [128][64] | Bs [128][64]
    int bid = blockIdx.x;               // 1280 blocks
    int c8id = bid & 7, t2 = bid >> 3;  // t2 in [0,160)
    int jt = t2 % 4, q_ = t2 / 4;       // q_ in [0,40)
    int itb = q_ * 8 + c8id;            // [0,320)
    int it = itb % 5, b = itb / 5;
    int j0 = jt * 128, i0 = it * 128;   // j = channel (M), i = token (N)
    int t = threadIdx.x;
    int w = t >> 6, lane = t & 63, quad = lane >> 4, l15 = lane & 15;
    int wr = w >> 1, wc = w & 1;
    f32x4 acc[4][4] = {};
    const u16* abase = woT + (size_t)j0 * DDIM;
    const u16* bbase = attnout + ((size_t)b * NTOK + i0) * DDIM;
    for (int k0 = 0; k0 < DDIM; k0 += 64) {
        __syncthreads();
#pragma unroll
        for (int c = 0; c < 4; c++) {
            int unit = c * 256 + t;
            int row = unit >> 3, cc = unit & 7;
            int gcol = (cc ^ (row & 7)) * 8;
            glds16(abase + (size_t)row * DDIM + k0 + gcol, SMEM + unit * 8);
            glds16(bbase + (size_t)row * DDIM + k0 + gcol, SMEM + 8192 + unit * 8);
        }
        __syncthreads();
#pragma unroll
        for (int kk = 0; kk < 2; kk++) {
            bf16x8 af[4], bfv[4];
            int chA = (((kk * 4 + quad) ^ (l15 & 7))) * 8;
#pragma unroll
            for (int q2 = 0; q2 < 4; q2++) {
                af[q2]  = *(const bf16x8*)&SMEM[(wr * 64 + q2 * 16 + l15) * 64 + chA];
                bfv[q2] = *(const bf16x8*)&SMEM[8192 + (wc * 64 + q2 * 16 + l15) * 64 + chA];
            }
#pragma unroll
            for (int ii = 0; ii < 4; ii++)
#pragma unroll
                for (int jj = 0; jj < 4; jj++)
                    acc[ii][jj] = __builtin_amdgcn_mfma_f32_16x16x32_bf16(af[ii], bfv[jj], acc[ii][jj], 0, 0, 0);
        }
    }
    // D rows = channel, cols = token -> coalesced (b, d, n) f32 store
#pragma unroll
    for (int ii = 0; ii < 4; ii++)
#pragma unroll
        for (int jj = 0; jj < 4; jj++) {
            int gi = i0 + wc * 64 + jj * 16 + l15;
            if (gi >= NTOK) continue;
#pragma unroll
            for (int r = 0; r < 4; r++) {
                int gj = j0 + wr * 64 + ii * 16 + quad * 4 + r;
                out[((size_t)b * DDIM + gj) * NTOK + gi] = acc[ii][jj][r];
            }
        }
}

extern "C" void kernel_launch(void* const* d_in, const int* in_sizes, int n_in,
                              void* d_out, int out_size, void* d_ws, size_t ws_size,
                              hipStream_t stream) {
    const float* x    = (const float*)d_in[0];   // (64,512,25,25) f32
    const float* wqkv = (const float*)d_in[1];   // (512,1536) f32
    const float* wout = (const float*)d_in[2];   // (512,512) f32
    const float* rpb  = (const float*)d_in[3];   // (2401,8) f32
    const int*   rpi  = (const int*)d_in[4];     // (625,625) int32
    float* out = (float*)d_out;

    char* ws = (char*)d_ws;
    size_t off = 0;
    auto alloc = [&](size_t nbytes) -> void* {
        void* p = ws + off;
        off += (nbytes + 255) & ~(size_t)255;
        return p;
    };
    u16* tokens   = (u16*)alloc((size_t)NB * NTOK * DDIM * 2);     // 41 MB (reused as attnout)
    u16* qk       = (u16*)alloc((size_t)NB * NTOK * 1024 * 2);     // 82 MB
    u16* vT       = (u16*)alloc((size_t)NB * NH * DH * NTOKP * 2); // 42 MB
    u16* wqkvT    = (u16*)alloc((size_t)1536 * DDIM * 2);
    u16* woutT    = (u16*)alloc((size_t)DDIM * DDIM * 2);
    float* biasCf = (float*)alloc((size_t)NH * 100 * 4096 * 4);    // 13.1 MB, C-layout f32
    u16* attnout  = tokens;  // tokens is dead after k_qkv

    k_transpose_x<<<dim3(10, 8, NB), 256, 0, stream>>>(x, tokens);
    k_transpose_w<<<dim3(1536 / 64, DDIM / 64), 256, 0, stream>>>(wqkv, wqkvT, DDIM, 1536);
    k_transpose_w<<<dim3(DDIM / 64, DDIM / 64), 256, 0, stream>>>(wout, woutT, DDIM, DDIM);
    k_bias<<<dim3(800), 256, 0, stream>>>(rpi, rpb, biasCf);
    k_qkv<<<dim3(3840), 256, 0, stream>>>(tokens, wqkvT, qk, vT);
    k_attn<<<dim3(5120), 256, 0, stream>>>(qk, vT, biasCf, attnout);
    k_out<<<dim3(1280), 256, 0, stream>>>(attnout, woutT, out);
}

// Round 5
// 419.470 us; speedup vs baseline: 1.2130x; 1.2130x over previous
//
#include <hip/hip_runtime.h>
#include <cstdint>
#include <cstddef>

typedef unsigned short u16;
typedef __attribute__((ext_vector_type(8))) short bf16x8;   // 8 bf16 = 4 VGPRs
typedef __attribute__((ext_vector_type(4))) float f32x4;    // MFMA 16x16 accum

#define NB    64    // batch
#define NTOK  625   // tokens (25x25)
#define NTOKP 640   // padded tokens (rows 625..639 are zero everywhere)
#define DDIM  512
#define NH    8
#define DH    64

__device__ __forceinline__ float bf2f(u16 v) {
    return __uint_as_float(((unsigned int)v) << 16);
}
__device__ __forceinline__ u16 f2bf(float f) {           // RNE
    unsigned int x = __float_as_uint(f);
    unsigned int r = (x + 0x7fffu + ((x >> 16) & 1u)) >> 16;
    return (u16)r;
}
__device__ __forceinline__ u16 f2bf_fast(float f) {      // round-half-up (2 ops)
    return (u16)((__float_as_uint(f) + 0x8000u) >> 16);
}

// async global->LDS, 16B per lane (m97 pattern); fallback = sync staging
#if __has_builtin(__builtin_amdgcn_global_load_lds)
typedef const __attribute__((address_space(1))) void gas_void;
typedef __attribute__((address_space(3))) void las_void;
__device__ __forceinline__ void glds16(const void* g, void* l) {
    __builtin_amdgcn_global_load_lds((gas_void*)g, (las_void*)l, 16, 0, 0);
}
#else
__device__ __forceinline__ void glds16(const void* g, void* l) {
    *(uint4*)l = *(const uint4*)g;
}
#endif

// ---------------- transpose x: f32 (b, d, n) -> bf16 tokens (b, 640, d), zero pad ----
__global__ __launch_bounds__(256) void k_transpose_x(const float* __restrict__ x,
                                                     u16* __restrict__ tokens) {
    __shared__ u16 T[64][66];
    int b = blockIdx.z, ct = blockIdx.y, it = blockIdx.x;
    int t = threadIdx.x;
    int i0 = it * 64, c0 = ct * 64;
#pragma unroll
    for (int r = 0; r < 2; r++) {
        int c = (t >> 3) + r * 32;
        int i8 = (t & 7) * 8;
        const float* s = x + ((size_t)b * DDIM + c0 + c) * NTOK + i0 + i8;
#pragma unroll
        for (int u = 0; u < 8; u++)
            T[c][i8 + u] = (i0 + i8 + u < NTOK) ? f2bf(s[u]) : (u16)0;
    }
    __syncthreads();
#pragma unroll
    for (int r = 0; r < 2; r++) {
        int i = (t >> 3) + r * 32;
        int c8 = (t & 7) * 8;
        int gi = i0 + i;                // gi <= 639: always stored (zeros in pad rows)
        u16* d = tokens + ((size_t)b * NTOKP + gi) * DDIM + c0 + c8;
#pragma unroll
        for (int u = 0; u < 8; u++) d[u] = T[c8 + u][i];
    }
}

// ---------------- weight transpose: f32 src[R][C] -> bf16 dst[C][R] ----------------
__global__ __launch_bounds__(256) void k_transpose_w(const float* __restrict__ src,
                                                     u16* __restrict__ dst, int R, int C) {
    __shared__ u16 T[64][66];
    int r0 = blockIdx.y * 64, c0 = blockIdx.x * 64;
    int t = threadIdx.x;
#pragma unroll
    for (int rr = 0; rr < 2; rr++) {
        int r = (t >> 3) + rr * 32;
        int c8 = (t & 7) * 8;
        const float* s = src + (size_t)(r0 + r) * C + c0 + c8;
#pragma unroll
        for (int u = 0; u < 8; u++) T[r][c8 + u] = f2bf(s[u]);
    }
    __syncthreads();
#pragma unroll
    for (int rr = 0; rr < 2; rr++) {
        int c = (t >> 3) + rr * 32;
        int r8 = (t & 7) * 8;
        u16* d = dst + (size_t)(c0 + c) * R + r0 + r8;
#pragma unroll
        for (int u = 0; u < 8; u++) d[u] = T[r8 + u][c];
    }
}

// ---------------- bias expand into MFMA C-layout (f32), masking folded in ----------
__global__ __launch_bounds__(256) void k_bias(const int* __restrict__ rpi,
                                              const float* __restrict__ rpb,
                                              float* __restrict__ biasCf) {
    int blk = blockIdx.x;               // 800 = m*100 + jt*10 + it
    int m = blk / 100, jt = (blk / 10) % 10, it = blk % 10;
    int t = threadIdx.x;
    float vals[16];
#pragma unroll
    for (int jj = 0; jj < 4; jj++) {
        int gj = jt * 64 + jj * 16 + (t & 15);
#pragma unroll
        for (int r = 0; r < 4; r++) {
            int gi = it * 64 + (t >> 6) * 16 + ((t >> 4) & 3) * 4 + r;
            float v;
            if (gj >= NTOK) v = -1e30f;
            else if (gi >= NTOK) v = 0.f;
            else v = rpb[rpi[gi * NTOK + gj] * NH + m];
            vals[jj * 4 + r] = v;
        }
    }
    float* d = biasCf + ((size_t)(m * 10 + jt) * 10 + it) * 4096 + t * 16;
#pragma unroll
    for (int g = 0; g < 4; g++)
        *(f32x4*)(d + g * 4) = *(f32x4*)&vals[g * 4];
}

// ---------------- QKV GEMM: BK=32, XCD swizzle, conflict-free chunk swizzle ---------
// q (scaled 0.125) -> qk[b][i][0..511]; k -> qk[b][i][512..1023] (i over 640 rows);
// v -> vT[b][hd][tc][n'] with n' = tile*64 + pi(tok), pi(v) = (v&15)*4 + (v>>4).
__global__ __launch_bounds__(256, 4) void k_qkv(const u16* __restrict__ tokens,
                                                const u16* __restrict__ wT,
                                                u16* __restrict__ qk, u16* __restrict__ vT) {
    __shared__ u16 SMEM[9216];          // As [128][32] | Bs [128][32]; reused in epilogue
    // XCD swizzle: the 12 jt-blocks sharing one A-slab land on one XCD (bid%8)
    int bid = blockIdx.x;               // 3840 blocks
    int c8id = bid & 7, t2 = bid >> 3;  // t2 in [0,480)
    int jt = t2 % 12, q_ = t2 / 12;     // q_ in [0,40)
    int itb = q_ * 8 + c8id;            // [0,320)
    int it = itb % 5, b = itb / 5;
    int i0 = it * 128, j0 = jt * 128;
    int t = threadIdx.x;
    int w = t >> 6, lane = t & 63, quad = lane >> 4, l15 = lane & 15;
    int wr = w >> 1, wc = w & 1;
    int swl = (l15 + (l15 >> 2)) & 3;   // read-side chunk swizzle
    f32x4 acc[4][4] = {};
    const u16* abase = tokens + ((size_t)b * NTOKP + i0) * DDIM;
    const u16* bbase = wT + (size_t)j0 * DDIM;
    for (int k0 = 0; k0 < DDIM; k0 += 32) {
        __syncthreads();
#pragma unroll
        for (int c = 0; c < 2; c++) {
            int unit = c * 256 + t;
            int row = unit >> 2, cc = unit & 3;
            int gcol = (cc ^ ((row + (row >> 2)) & 3)) * 8;   // store-side swizzle via src
            glds16(abase + (size_t)row * DDIM + k0 + gcol, SMEM + unit * 8);
            glds16(bbase + (size_t)row * DDIM + k0 + gcol, SMEM + 4096 + unit * 8);
        }
        __syncthreads();
        bf16x8 af[4], bfv[4];
        int chA = (quad ^ swl) * 8;
#pragma unroll
        for (int q2 = 0; q2 < 4; q2++) {
            af[q2]  = *(const bf16x8*)&SMEM[(wr * 64 + q2 * 16 + l15) * 32 + chA];
            bfv[q2] = *(const bf16x8*)&SMEM[4096 + (wc * 64 + q2 * 16 + l15) * 32 + chA];
        }
#pragma unroll
        for (int ii = 0; ii < 4; ii++)
#pragma unroll
            for (int jj = 0; jj < 4; jj++)
                acc[ii][jj] = __builtin_amdgcn_mfma_f32_16x16x32_bf16(af[ii], bfv[jj], acc[ii][jj], 0, 0, 0);
    }
    __syncthreads();                    // SMEM reuse
    if (jt < 8) {
        // q/k epilogue via T2[64][136]: rows=token half, cols=128 channels (pad rows: zeros)
        float scale = (j0 < 512) ? 0.125f : 1.0f;
#pragma unroll
        for (int h = 0; h < 2; h++) {
            if (h) __syncthreads();
            if (wr == h) {
#pragma unroll
                for (int ii = 0; ii < 4; ii++)
#pragma unroll
                    for (int jj = 0; jj < 4; jj++)
#pragma unroll
                        for (int r = 0; r < 4; r++)
                            SMEM[(ii * 16 + quad * 4 + r) * 136 + wc * 64 + jj * 16 + l15] =
                                f2bf(acc[ii][jj][r] * scale);
            }
            __syncthreads();
#pragma unroll
            for (int g = 0; g < 4; g++) {
                int unit = g * 256 + t;
                int tok = unit >> 4, ch8 = (unit & 15) * 8;
                *(uint4*)(qk + ((size_t)b * NTOKP + i0 + h * 64 + tok) * 1024 + j0 + ch8) =
                    *(uint4*)&SMEM[tok * 136 + ch8];
            }
        }
    } else {
        // v epilogue via T[128][72]: rows=channel, cols=pi(token); pad tokens are zero
        int ch0 = j0 - 1024;
#pragma unroll
        for (int h = 0; h < 2; h++) {
            if (h) __syncthreads();
            if (wr == h) {
#pragma unroll
                for (int ii = 0; ii < 4; ii++)
#pragma unroll
                    for (int jj = 0; jj < 4; jj++)
#pragma unroll
                        for (int r = 0; r < 4; r++) {
                            int tok = ii * 16 + quad * 4 + r;   // within 64-half
                            SMEM[(wc * 64 + jj * 16 + l15) * 72 + (tok & 15) * 4 + (tok >> 4)] =
                                f2bf(acc[ii][jj][r]);
                        }
            }
            __syncthreads();
#pragma unroll
            for (int g = 0; g < 4; g++) {
                int unit = g * 256 + t;
                int chl = unit >> 3, tok8 = (unit & 7) * 8;
                int chv = ch0 + chl, hd = chv >> 6, tc = chv & 63;
                *(uint4*)(vT + (((size_t)b * NH + hd) * DH + tc) * NTOKP + i0 + h * 64 + tok8) =
                    *(uint4*)&SMEM[chl * 72 + tok8];
            }
        }
    }
}

// ---------------- attention: branch-free staging, hoisted invariant frags ----------
__global__ __launch_bounds__(256) void k_attn(const u16* __restrict__ qk,
                                              const u16* __restrict__ vT,
                                              const float* __restrict__ biasCf,
                                              u16* __restrict__ attnout) {
    __shared__ u16 Qs[64][72];
    __shared__ u16 Ks[64][72];
    __shared__ u16 Vs[80][72];          // rows 64..79 = 1.0 (row-sum ones tile)
    __shared__ u16 Ps[64][72];
    // XCD swizzle: the 10 i-tiles sharing one head's K/V land on one XCD
    int bid = blockIdx.x;               // 5120 blocks
    int c8id = bid & 7, t2 = bid >> 3;  // t2 in [0,640)
    int it = t2 % 10, q_ = t2 / 10;     // q_ in [0,64)
    int bm = q_ * 8 + c8id;             // [0,512)
    int m = bm & 7, b = bm >> 3;
    int i0 = it * 64;
    int t = threadIdx.x;
    int w = t >> 6, lane = t & 63, quad = lane >> 4, l15 = lane & 15;
    {   // ones rows for the sum tile
        int row = 64 + (t >> 4), c4 = (t & 15) * 4;
        *(uint2*)&Vs[row][c4] = make_uint2(0x3F803F80u, 0x3F803F80u);
    }
#pragma unroll
    for (int r = 0; r < 2; r++) {       // Q tile — unconditional (640-row qk)
        int row = (t >> 3) + r * 32;
        int t8 = (t & 7) * 8;
        *(uint4*)&Qs[row][t8] =
            *(const uint4*)(qk + ((size_t)b * NTOKP + i0 + row) * 1024 + m * DH + t8);
    }
    __syncthreads();
    bf16x8 aq[2], vones[2];             // loop-invariant fragments, hoisted
#pragma unroll
    for (int kk = 0; kk < 2; kk++) {
        aq[kk]    = *(const bf16x8*)&Qs[w * 16 + l15][kk * 32 + quad * 8];
        vones[kk] = *(const bf16x8*)&Vs[64 + l15][kk * 32 + quad * 8];
    }
    f32x4 oacc[5] = {};                 // [4] = row sums (ones tile)
    const u16* vbase = vT + ((size_t)b * NH + m) * DH * NTOKP;
    const float* bC = biasCf + (size_t)(m * 100 + it) * 4096 + t * 16;

    for (int jt = 0; jt < 10; jt++) {
        int j0 = jt * 64;
        __syncthreads();                // prior Ks/Vs reads done
#pragma unroll
        for (int r = 0; r < 2; r++) {   // stage K (rows=j) and V (rows=dh, pi-token cols)
            int row = (t >> 3) + r * 32;
            int c8 = (t & 7) * 8;
            *(uint4*)&Ks[row][c8] =
                *(const uint4*)(qk + ((size_t)b * NTOKP + j0 + row) * 1024 + 512 + m * DH + c8);
            *(uint4*)&Vs[row][c8] = *(const uint4*)(vbase + (size_t)row * NTOKP + j0 + c8);
        }
        __syncthreads();
        // S init = f32 C-layout bias (masking pre-folded)
        const float* bp = bC + (size_t)jt * 10 * 4096;
        f32x4 s[4];
#pragma unroll
        for (int jj = 0; jj < 4; jj++) s[jj] = *(const f32x4*)(bp + jj * 4);
#pragma unroll
        for (int jj = 0; jj < 4; jj++)
#pragma unroll
            for (int kk = 0; kk < 2; kk++) {
                bf16x8 bk = *(const bf16x8*)&Ks[jj * 16 + l15][kk * 32 + quad * 8];
                s[jj] = __builtin_amdgcn_mfma_f32_16x16x32_bf16(aq[kk], bk, s[jj], 0, 0, 0);
            }
        // P = exp(S); constant shift cancels in normalization (bounded scores)
#pragma unroll
        for (int r = 0; r < 4; r++) {
            float p0 = __expf(s[0][r]), p1 = __expf(s[1][r]);
            float p2 = __expf(s[2][r]), p3 = __expf(s[3][r]);
            uint2 pk;
            pk.x = (unsigned)f2bf_fast(p0) | ((unsigned)f2bf_fast(p1) << 16);
            pk.y = (unsigned)f2bf_fast(p2) | ((unsigned)f2bf_fast(p3) << 16);
            // pi-packed P row: col = l15*4 + jj  (matches vT token order)
            *(uint2*)&Ps[w * 16 + quad * 4 + r][l15 * 4] = pk;
        }
        // same-wave rows only -> no barrier needed before re-read
        bf16x8 ap[2];
#pragma unroll
        for (int kk = 0; kk < 2; kk++)
            ap[kk] = *(const bf16x8*)&Ps[w * 16 + l15][kk * 32 + quad * 8];
#pragma unroll
        for (int tt = 0; tt < 4; tt++)
#pragma unroll
            for (int kk = 0; kk < 2; kk++) {
                bf16x8 bv = *(const bf16x8*)&Vs[tt * 16 + l15][kk * 32 + quad * 8];
                oacc[tt] = __builtin_amdgcn_mfma_f32_16x16x32_bf16(ap[kk], bv, oacc[tt], 0, 0, 0);
            }
#pragma unroll
        for (int kk = 0; kk < 2; kk++)
            oacc[4] = __builtin_amdgcn_mfma_f32_16x16x32_bf16(ap[kk], vones[kk], oacc[4], 0, 0, 0);
    }
    float rinv[4];
#pragma unroll
    for (int r = 0; r < 4; r++) rinv[r] = __frcp_rn(oacc[4][r]);
#pragma unroll
    for (int tt = 0; tt < 4; tt++)
#pragma unroll
        for (int r = 0; r < 4; r++) {
            int gi = i0 + w * 16 + quad * 4 + r;
            if (gi < NTOK)              // keep: preserves zero pad rows of attnout
                attnout[((size_t)b * NTOKP + gi) * DDIM + m * DH + tt * 16 + l15] =
                    f2bf(oacc[tt][r] * rinv[r]);
        }
}

// ---------------- out GEMM (C^T): BK=32, XCD swizzle, chunk swizzle ----------------
__global__ __launch_bounds__(256, 4) void k_out(const u16* __restrict__ attnout,
                                                const u16* __restrict__ woT,
                                                float* __restrict__ out) {
    __shared__ u16 SMEM[8192];          // As [128][32] | Bs [128][32]
    int bid = blockIdx.x;               // 1280 blocks
    int c8id = bid & 7, t2 = bid >> 3;  // t2 in [0,160)
    int jt = t2 % 4, q_ = t2 / 4;       // q_ in [0,40)
    int itb = q_ * 8 + c8id;            // [0,320)
    int it = itb % 5, b = itb / 5;
    int j0 = jt * 128, i0 = it * 128;   // j = channel (M), i = token (N)
    int t = threadIdx.x;
    int w = t >> 6, lane = t & 63, quad = lane >> 4, l15 = lane & 15;
    int wr = w >> 1, wc = w & 1;
    int swl = (l15 + (l15 >> 2)) & 3;
    f32x4 acc[4][4] = {};
    const u16* abase = woT + (size_t)j0 * DDIM;
    const u16* bbase = attnout + ((size_t)b * NTOKP + i0) * DDIM;
    for (int k0 = 0; k0 < DDIM; k0 += 32) {
        __syncthreads();
#pragma unroll
        for (int c = 0; c < 2; c++) {
            int unit = c * 256 + t;
            int row = unit >> 2, cc = unit & 3;
            int gcol = (cc ^ ((row + (row >> 2)) & 3)) * 8;
            glds16(abase + (size_t)row * DDIM + k0 + gcol, SMEM + unit * 8);
            glds16(bbase + (size_t)row * DDIM + k0 + gcol, SMEM + 4096 + unit * 8);
        }
        __syncthreads();
        bf16x8 af[4], bfv[4];
        int chA = (quad ^ swl) * 8;
#pragma unroll
        for (int q2 = 0; q2 < 4; q2++) {
            af[q2]  = *(const bf16x8*)&SMEM[(wr * 64 + q2 * 16 + l15) * 32 + chA];
            bfv[q2] = *(const bf16x8*)&SMEM[4096 + (wc * 64 + q2 * 16 + l15) * 32 + chA];
        }
#pragma unroll
        for (int ii = 0; ii < 4; ii++)
#pragma unroll
            for (int jj = 0; jj < 4; jj++)
                acc[ii][jj] = __builtin_amdgcn_mfma_f32_16x16x32_bf16(af[ii], bfv[jj], acc[ii][jj], 0, 0, 0);
    }
    // D rows = channel, cols = token -> coalesced (b, d, n) f32 store
#pragma unroll
    for (int ii = 0; ii < 4; ii++)
#pragma unroll
        for (int jj = 0; jj < 4; jj++) {
            int gi = i0 + wc * 64 + jj * 16 + l15;
            if (gi >= NTOK) continue;
#pragma unroll
            for (int r = 0; r < 4; r++) {
                int gj = j0 + wr * 64 + ii * 16 + quad * 4 + r;
                out[((size_t)b * DDIM + gj) * NTOK + gi] = acc[ii][jj][r];
            }
        }
}

extern "C" void kernel_launch(void* const* d_in, const int* in_sizes, int n_in,
                              void* d_out, int out_size, void* d_ws, size_t ws_size,
                              hipStream_t stream) {
    const float* x    = (const float*)d_in[0];   // (64,512,25,25) f32
    const float* wqkv = (const float*)d_in[1];   // (512,1536) f32
    const float* wout = (const float*)d_in[2];   // (512,512) f32
    const float* rpb  = (const float*)d_in[3];   // (2401,8) f32
    const int*   rpi  = (const int*)d_in[4];     // (625,625) int32
    float* out = (float*)d_out;

    char* ws = (char*)d_ws;
    size_t off = 0;
    auto alloc = [&](size_t nbytes) -> void* {
        void* p = ws + off;
        off += (nbytes + 255) & ~(size_t)255;
        return p;
    };
    u16* tokens   = (u16*)alloc((size_t)NB * NTOKP * DDIM * 2);    // 42 MB (reused as attnout)
    u16* qk       = (u16*)alloc((size_t)NB * NTOKP * 1024 * 2);    // 84 MB
    u16* vT       = (u16*)alloc((size_t)NB * NH * DH * NTOKP * 2); // 42 MB
    u16* wqkvT    = (u16*)alloc((size_t)1536 * DDIM * 2);
    u16* woutT    = (u16*)alloc((size_t)DDIM * DDIM * 2);
    float* biasCf = (float*)alloc((size_t)NH * 100 * 4096 * 4);    // 13.1 MB, C-layout f32
    u16* attnout  = tokens;  // tokens is dead after k_qkv; pad rows stay zero

    k_transpose_x<<<dim3(10, 8, NB), 256, 0, stream>>>(x, tokens);
    k_transpose_w<<<dim3(1536 / 64, DDIM / 64), 256, 0, stream>>>(wqkv, wqkvT, DDIM, 1536);
    k_transpose_w<<<dim3(DDIM / 64, DDIM / 64), 256, 0, stream>>>(wout, woutT, DDIM, DDIM);
    k_bias<<<dim3(800), 256, 0, stream>>>(rpi, rpb, biasCf);
    k_qkv<<<dim3(3840), 256, 0, stream>>>(tokens, wqkvT, qk, vT);
    k_attn<<<dim3(5120), 256, 0, stream>>>(qk, vT, biasCf, attnout);
    k_out<<<dim3(1280), 256, 0, stream>>>(attnout, woutT, out);
}

// Round 6
// 409.151 us; speedup vs baseline: 1.2435x; 1.0252x over previous
//
#include <hip/hip_runtime.h>
#include <cstdint>
#include <cstddef>

typedef unsigned short u16;
typedef __attribute__((ext_vector_type(8))) short bf16x8;   // 8 bf16 = 4 VGPRs
typedef __attribute__((ext_vector_type(4))) float f32x4;    // MFMA 16x16 accum

#define NB    64    // batch
#define NTOK  625   // tokens (25x25)
#define NTOKP 640   // padded tokens (rows 625..639 are zero everywhere)
#define DDIM  512
#define NH    8
#define DH    64
#define LOG2E 1.44269504088896f

__device__ __forceinline__ float bf2f(u16 v) {
    return __uint_as_float(((unsigned int)v) << 16);
}
__device__ __forceinline__ u16 f2bf(float f) {           // RNE
    unsigned int x = __float_as_uint(f);
    unsigned int r = (x + 0x7fffu + ((x >> 16) & 1u)) >> 16;
    return (u16)r;
}
__device__ __forceinline__ float fexp2(float x) {
#if __has_builtin(__builtin_amdgcn_exp2f)
    return __builtin_amdgcn_exp2f(x);
#else
    return exp2f(x);
#endif
}
// pack two f32 -> bf16x2 (round-half-up), 3 VALU ops
__device__ __forceinline__ unsigned pack_bf16(float a, float b) {
#if __has_builtin(__builtin_amdgcn_perm)
    return __builtin_amdgcn_perm(__float_as_uint(b) + 0x8000u,
                                 __float_as_uint(a) + 0x8000u, 0x07060302u);
#else
    return ((__float_as_uint(a) + 0x8000u) >> 16) |
           (((__float_as_uint(b) + 0x8000u) >> 16) << 16);
#endif
}

// async global->LDS, 16B per lane (m97 pattern); fallback = sync staging
#if __has_builtin(__builtin_amdgcn_global_load_lds)
typedef const __attribute__((address_space(1))) void gas_void;
typedef __attribute__((address_space(3))) void las_void;
__device__ __forceinline__ void glds16(const void* g, void* l) {
    __builtin_amdgcn_global_load_lds((gas_void*)g, (las_void*)l, 16, 0, 0);
}
#else
__device__ __forceinline__ void glds16(const void* g, void* l) {
    *(uint4*)l = *(const uint4*)g;
}
#endif

// ---------------- transpose x: f32 (b, d, n) -> bf16 tokens (b, 640, d), zero pad ----
__global__ __launch_bounds__(256) void k_transpose_x(const float* __restrict__ x,
                                                     u16* __restrict__ tokens) {
    __shared__ u16 T[64][66];
    int b = blockIdx.z, ct = blockIdx.y, it = blockIdx.x;
    int t = threadIdx.x;
    int i0 = it * 64, c0 = ct * 64;
#pragma unroll
    for (int r = 0; r < 2; r++) {
        int c = (t >> 3) + r * 32;
        int i8 = (t & 7) * 8;
        const float* s = x + ((size_t)b * DDIM + c0 + c) * NTOK + i0 + i8;
#pragma unroll
        for (int u = 0; u < 8; u++)
            T[c][i8 + u] = (i0 + i8 + u < NTOK) ? f2bf(s[u]) : (u16)0;
    }
    __syncthreads();
#pragma unroll
    for (int r = 0; r < 2; r++) {
        int i = (t >> 3) + r * 32;
        int c8 = (t & 7) * 8;
        int gi = i0 + i;                // gi <= 639: always stored (zeros in pad rows)
        u16* d = tokens + ((size_t)b * NTOKP + gi) * DDIM + c0 + c8;
#pragma unroll
        for (int u = 0; u < 8; u++) d[u] = T[c8 + u][i];
    }
}

// ---------------- weight transpose: f32 src[R][C] -> bf16 dst[C][R] ----------------
__global__ __launch_bounds__(256) void k_transpose_w(const float* __restrict__ src,
                                                     u16* __restrict__ dst, int R, int C) {
    __shared__ u16 T[64][66];
    int r0 = blockIdx.y * 64, c0 = blockIdx.x * 64;
    int t = threadIdx.x;
#pragma unroll
    for (int rr = 0; rr < 2; rr++) {
        int r = (t >> 3) + rr * 32;
        int c8 = (t & 7) * 8;
        const float* s = src + (size_t)(r0 + r) * C + c0 + c8;
#pragma unroll
        for (int u = 0; u < 8; u++) T[r][c8 + u] = f2bf(s[u]);
    }
    __syncthreads();
#pragma unroll
    for (int rr = 0; rr < 2; rr++) {
        int c = (t >> 3) + rr * 32;
        int r8 = (t & 7) * 8;
        u16* d = dst + (size_t)(c0 + c) * R + r0 + r8;
#pragma unroll
        for (int u = 0; u < 8; u++) d[u] = T[r8 + u][c];
    }
}

// ---------------- bias expand into MFMA C-layout (f32, log2 domain), masks folded ---
__global__ __launch_bounds__(256) void k_bias(const int* __restrict__ rpi,
                                              const float* __restrict__ rpb,
                                              float* __restrict__ biasCf) {
    int blk = blockIdx.x;               // 800 = m*100 + jt*10 + it
    int m = blk / 100, jt = (blk / 10) % 10, it = blk % 10;
    int t = threadIdx.x;
    float vals[16];
#pragma unroll
    for (int jj = 0; jj < 4; jj++) {
        int gj = jt * 64 + jj * 16 + (t & 15);
#pragma unroll
        for (int r = 0; r < 4; r++) {
            int gi = it * 64 + (t >> 6) * 16 + ((t >> 4) & 3) * 4 + r;
            float v;
            if (gj >= NTOK) v = -1e30f;
            else if (gi >= NTOK) v = 0.f;
            else v = rpb[rpi[gi * NTOK + gj] * NH + m];
            vals[jj * 4 + r] = v * LOG2E;
        }
    }
    float* d = biasCf + ((size_t)(m * 10 + jt) * 10 + it) * 4096 + t * 16;
#pragma unroll
    for (int g = 0; g < 4; g++)
        *(f32x4*)(d + g * 4) = *(f32x4*)&vals[g * 4];
}

// ---------------- QKV GEMM: dbuf single-barrier K-loop, XCD+chunk swizzles ----------
// q (scaled 0.125*log2e) -> qk[b][i][0..511]; k -> qk[b][i][512..1023] (640 rows);
// v -> vT[b][hd][tc][n'] with n' = tile*64 + pi(tok), pi(v) = (v&15)*4 + (v>>4).
__global__ __launch_bounds__(256, 4) void k_qkv(const u16* __restrict__ tokens,
                                                const u16* __restrict__ wT,
                                                u16* __restrict__ qk, u16* __restrict__ vT) {
    __shared__ u16 SMEM[16384];         // A dbuf 2x[128][32] | B dbuf 2x[128][32]; epilogue reuse
    int bid = blockIdx.x;               // 3840 blocks; bid%8 -> XCD co-location
    int c8id = bid & 7, t2 = bid >> 3;
    int jt = t2 % 12, q_ = t2 / 12;
    int itb = q_ * 8 + c8id;
    int it = itb % 5, b = itb / 5;
    int i0 = it * 128, j0 = jt * 128;
    int t = threadIdx.x;
    int w = t >> 6, lane = t & 63, quad = lane >> 4, l15 = lane & 15;
    int wr = w >> 1, wc = w & 1;
    int swl = (l15 + (l15 >> 2)) & 3;   // read-side chunk swizzle
    const u16* abase = tokens + ((size_t)b * NTOKP + i0) * DDIM;
    const u16* bbase = wT + (size_t)j0 * DDIM;
    auto stage = [&](int k0, int buf) {
#pragma unroll
        for (int c = 0; c < 2; c++) {
            int unit = c * 256 + t;
            int row = unit >> 2, cc = unit & 3;
            int gcol = (cc ^ ((row + (row >> 2)) & 3)) * 8;   // store-side swizzle via src
            glds16(abase + (size_t)row * DDIM + k0 + gcol, SMEM + buf * 4096 + unit * 8);
            glds16(bbase + (size_t)row * DDIM + k0 + gcol, SMEM + 8192 + buf * 4096 + unit * 8);
        }
    };
    stage(0, 0);
    __syncthreads();
    f32x4 acc[4][4] = {};
    for (int k0 = 0; k0 < DDIM; k0 += 32) {
        int pc = (k0 >> 5) & 1;
        if (k0 + 32 < DDIM) stage(k0 + 32, pc ^ 1);   // in flight across this iter's compute
        bf16x8 af[4], bfv[4];
        int chA = (quad ^ swl) * 8;
#pragma unroll
        for (int q2 = 0; q2 < 4; q2++) {
            af[q2]  = *(const bf16x8*)&SMEM[pc * 4096 + (wr * 64 + q2 * 16 + l15) * 32 + chA];
            bfv[q2] = *(const bf16x8*)&SMEM[8192 + pc * 4096 + (wc * 64 + q2 * 16 + l15) * 32 + chA];
        }
#pragma unroll
        for (int ii = 0; ii < 4; ii++)
#pragma unroll
            for (int jj = 0; jj < 4; jj++)
                acc[ii][jj] = __builtin_amdgcn_mfma_f32_16x16x32_bf16(af[ii], bfv[jj], acc[ii][jj], 0, 0, 0);
        __syncthreads();                // drains next-buf glds; all reads of cur done
    }
    if (jt < 8) {
        // q/k epilogue via T2[64][136]: rows=token half, cols=128 channels (pad rows: zeros)
        float scale = (j0 < 512) ? 0.125f * LOG2E : 1.0f;
#pragma unroll
        for (int h = 0; h < 2; h++) {
            if (h) __syncthreads();
            if (wr == h) {
#pragma unroll
                for (int ii = 0; ii < 4; ii++)
#pragma unroll
                    for (int jj = 0; jj < 4; jj++)
#pragma unroll
                        for (int r = 0; r < 4; r++)
                            SMEM[(ii * 16 + quad * 4 + r) * 136 + wc * 64 + jj * 16 + l15] =
                                f2bf(acc[ii][jj][r] * scale);
            }
            __syncthreads();
#pragma unroll
            for (int g = 0; g < 4; g++) {
                int unit = g * 256 + t;
                int tok = unit >> 4, ch8 = (unit & 15) * 8;
                *(uint4*)(qk + ((size_t)b * NTOKP + i0 + h * 64 + tok) * 1024 + j0 + ch8) =
                    *(uint4*)&SMEM[tok * 136 + ch8];
            }
        }
    } else {
        // v epilogue via T[128][72]: rows=channel, cols=pi(token); pad tokens are zero
        int ch0 = j0 - 1024;
#pragma unroll
        for (int h = 0; h < 2; h++) {
            if (h) __syncthreads();
            if (wr == h) {
#pragma unroll
                for (int ii = 0; ii < 4; ii++)
#pragma unroll
                    for (int jj = 0; jj < 4; jj++)
#pragma unroll
                        for (int r = 0; r < 4; r++) {
                            int tok = ii * 16 + quad * 4 + r;   // within 64-half
                            SMEM[(wc * 64 + jj * 16 + l15) * 72 + (tok & 15) * 4 + (tok >> 4)] =
                                f2bf(acc[ii][jj][r]);
                        }
            }
            __syncthreads();
#pragma unroll
            for (int g = 0; g < 4; g++) {
                int unit = g * 256 + t;
                int chl = unit >> 3, tok8 = (unit & 7) * 8;
                int chv = ch0 + chl, hd = chv >> 6, tc = chv & 63;
                *(uint4*)(vT + (((size_t)b * NH + hd) * DH + tc) * NTOKP + i0 + h * 64 + tok8) =
                    *(uint4*)&SMEM[chl * 72 + tok8];
            }
        }
    }
}

// ---------------- attention: glds dbuf staging, exp2 softmax, perm packing ----------
// LDS u16 layout: Qs[0,4096) | Ks 2x[4096,12288) | Vs 2x[12288,20480) | Ps[20480,25088)
__global__ __launch_bounds__(256, 3) void k_attn(const u16* __restrict__ qk,
                                                 const u16* __restrict__ vT,
                                                 const float* __restrict__ biasCf,
                                                 u16* __restrict__ attnout) {
    __shared__ u16 S[25088];
    int bid = blockIdx.x;               // 5120 blocks; bid%8 -> XCD co-location
    int c8id = bid & 7, t2 = bid >> 3;
    int it = t2 % 10, q_ = t2 / 10;
    int bm = q_ * 8 + c8id;
    int m = bm & 7, b = bm >> 3;
    int i0 = it * 64;
    int t = threadIdx.x;
    int w = t >> 6, lane = t & 63, quad = lane >> 4, l15 = lane & 15;

    const u16* qbase = qk + ((size_t)b * NTOKP + i0) * 1024 + m * DH;
    const u16* kbase = qk + (size_t)b * NTOKP * 1024 + 512 + m * DH;
    const u16* vbase = vT + ((size_t)b * NH + m) * DH * NTOKP;

    // stage Q tile (pitch-64 rows, XOR-chunk swizzle via source column)
#pragma unroll
    for (int c = 0; c < 2; c++) {
        int unit = c * 256 + t;
        int row = unit >> 3, pch = unit & 7;
        int gcol = (pch ^ (row & 7)) * 8;
        glds16(qbase + (size_t)row * 1024 + gcol, S + unit * 8);
    }
    // stage K/V for jt=0 into buf 0
#pragma unroll
    for (int c = 0; c < 2; c++) {
        int unit = c * 256 + t;
        int row = unit >> 3, pch = unit & 7;
        int gcol = (pch ^ (row & 7)) * 8;
        glds16(kbase + (size_t)row * 1024 + gcol, S + 4096 + unit * 8);
        glds16(vbase + (size_t)row * NTOKP + gcol, S + 12288 + unit * 8);
    }
    const float* bC = biasCf + (size_t)(m * 100 + it) * 4096 + t * 16;
    f32x4 ba[2][4];                     // bias prefetch ping-pong (log2 domain)
#pragma unroll
    for (int jj = 0; jj < 4; jj++) ba[0][jj] = *(const f32x4*)(bC + jj * 4);
    __syncthreads();                    // drains Q + buf0 + bias0

    bf16x8 aq[2];
#pragma unroll
    for (int kk = 0; kk < 2; kk++)
        aq[kk] = *(const bf16x8*)&S[(w * 16 + l15) * 64 + ((4 * kk + quad) ^ (l15 & 7)) * 8];
    bf16x8 vone;                        // constant 1.0 fragment (row-sum tile)
#pragma unroll
    for (int e = 0; e < 8; e++) vone[e] = (short)0x3F80;

    f32x4 oacc[5] = {};                 // [4] = row sums
#pragma unroll
    for (int jt = 0; jt < 10; jt++) {
        int p = jt & 1;
        if (jt < 9) {                   // prefetch bias + K/V for jt+1 (in flight this iter)
            const float* bp = bC + (size_t)(jt + 1) * 40960;
#pragma unroll
            for (int jj = 0; jj < 4; jj++) ba[p ^ 1][jj] = *(const f32x4*)(bp + jj * 4);
            int j1 = (jt + 1) * 64;
#pragma unroll
            for (int c = 0; c < 2; c++) {
                int unit = c * 256 + t;
                int row = unit >> 3, pch = unit & 7;
                int gcol = (pch ^ (row & 7)) * 8;
                glds16(kbase + (size_t)(j1 + row) * 1024 + gcol,
                       S + 4096 + (p ^ 1) * 4096 + unit * 8);
                glds16(vbase + (size_t)row * NTOKP + j1 + gcol,
                       S + 12288 + (p ^ 1) * 4096 + unit * 8);
            }
        }
        // S = bias + QK^T (log2 domain)
        f32x4 s[4];
#pragma unroll
        for (int jj = 0; jj < 4; jj++) s[jj] = ba[p][jj];
#pragma unroll
        for (int jj = 0; jj < 4; jj++)
#pragma unroll
            for (int kk = 0; kk < 2; kk++) {
                bf16x8 bk = *(const bf16x8*)&S[4096 + p * 4096 + (jj * 16 + l15) * 64 +
                                               ((4 * kk + quad) ^ (l15 & 7)) * 8];
                s[jj] = __builtin_amdgcn_mfma_f32_16x16x32_bf16(aq[kk], bk, s[jj], 0, 0, 0);
            }
        // P = exp2(S); pi-packed rows (col = l15*4 + jj matches vT token order)
#pragma unroll
        for (int r = 0; r < 4; r++) {
            float p0 = fexp2(s[0][r]), p1 = fexp2(s[1][r]);
            float p2 = fexp2(s[2][r]), p3 = fexp2(s[3][r]);
            uint2 pk;
            pk.x = pack_bf16(p0, p1);
            pk.y = pack_bf16(p2, p3);
            *(uint2*)&S[20480 + (w * 16 + quad * 4 + r) * 72 + l15 * 4] = pk;
        }
        // same-wave rows only -> no barrier before re-read
        bf16x8 ap[2];
#pragma unroll
        for (int kk = 0; kk < 2; kk++)
            ap[kk] = *(const bf16x8*)&S[20480 + (w * 16 + l15) * 72 + kk * 32 + quad * 8];
#pragma unroll
        for (int tt = 0; tt < 4; tt++)
#pragma unroll
            for (int kk = 0; kk < 2; kk++) {
                bf16x8 bv = *(const bf16x8*)&S[12288 + p * 4096 + (tt * 16 + l15) * 64 +
                                               ((4 * kk + quad) ^ (l15 & 7)) * 8];
                oacc[tt] = __builtin_amdgcn_mfma_f32_16x16x32_bf16(ap[kk], bv, oacc[tt], 0, 0, 0);
            }
#pragma unroll
        for (int kk = 0; kk < 2; kk++)
            oacc[4] = __builtin_amdgcn_mfma_f32_16x16x32_bf16(ap[kk], vone, oacc[4], 0, 0, 0);
        __syncthreads();                // drains next K/V glds; all reads of buf p done
    }
    float rinv[4];
#pragma unroll
    for (int r = 0; r < 4; r++) rinv[r] = __frcp_rn(oacc[4][r]);
#pragma unroll
    for (int tt = 0; tt < 4; tt++)
#pragma unroll
        for (int r = 0; r < 4; r++) {
            int gi = i0 + w * 16 + quad * 4 + r;
            if (gi < NTOK)              // keep: preserves zero pad rows of attnout
                attnout[((size_t)b * NTOKP + gi) * DDIM + m * DH + tt * 16 + l15] =
                    f2bf(oacc[tt][r] * rinv[r]);
        }
}

// ---------------- out GEMM (C^T): dbuf single-barrier, XCD+chunk swizzles -----------
__global__ __launch_bounds__(256, 4) void k_out(const u16* __restrict__ attnout,
                                                const u16* __restrict__ woT,
                                                float* __restrict__ out) {
    __shared__ u16 SMEM[16384];         // A dbuf | B dbuf
    int bid = blockIdx.x;               // 1280 blocks
    int c8id = bid & 7, t2 = bid >> 3;
    int jt = t2 % 4, q_ = t2 / 4;
    int itb = q_ * 8 + c8id;
    int it = itb % 5, b = itb / 5;
    int j0 = jt * 128, i0 = it * 128;   // j = channel (M), i = token (N)
    int t = threadIdx.x;
    int w = t >> 6, lane = t & 63, quad = lane >> 4, l15 = lane & 15;
    int wr = w >> 1, wc = w & 1;
    int swl = (l15 + (l15 >> 2)) & 3;
    const u16* abase = woT + (size_t)j0 * DDIM;
    const u16* bbase = attnout + ((size_t)b * NTOKP + i0) * DDIM;
    auto stage = [&](int k0, int buf) {
#pragma unroll
        for (int c = 0; c < 2; c++) {
            int unit = c * 256 + t;
            int row = unit >> 2, cc = unit & 3;
            int gcol = (cc ^ ((row + (row >> 2)) & 3)) * 8;
            glds16(abase + (size_t)row * DDIM + k0 + gcol, SMEM + buf * 4096 + unit * 8);
            glds16(bbase + (size_t)row * DDIM + k0 + gcol, SMEM + 8192 + buf * 4096 + unit * 8);
        }
    };
    stage(0, 0);
    __syncthreads();
    f32x4 acc[4][4] = {};
    for (int k0 = 0; k0 < DDIM; k0 += 32) {
        int pc = (k0 >> 5) & 1;
        if (k0 + 32 < DDIM) stage(k0 + 32, pc ^ 1);
        bf16x8 af[4], bfv[4];
        int chA = (quad ^ swl) * 8;
#pragma unroll
        for (int q2 = 0; q2 < 4; q2++) {
            af[q2]  = *(const bf16x8*)&SMEM[pc * 4096 + (wr * 64 + q2 * 16 + l15) * 32 + chA];
            bfv[q2] = *(const bf16x8*)&SMEM[8192 + pc * 4096 + (wc * 64 + q2 * 16 + l15) * 32 + chA];
        }
#pragma unroll
        for (int ii = 0; ii < 4; ii++)
#pragma unroll
            for (int jj = 0; jj < 4; jj++)
                acc[ii][jj] = __builtin_amdgcn_mfma_f32_16x16x32_bf16(af[ii], bfv[jj], acc[ii][jj], 0, 0, 0);
        __syncthreads();
    }
    // D rows = channel, cols = token -> coalesced (b, d, n) f32 store
#pragma unroll
    for (int ii = 0; ii < 4; ii++)
#pragma unroll
        for (int jj = 0; jj < 4; jj++) {
            int gi = i0 + wc * 64 + jj * 16 + l15;
            if (gi >= NTOK) continue;
#pragma unroll
            for (int r = 0; r < 4; r++) {
                int gj = j0 + wr * 64 + ii * 16 + quad * 4 + r;
                out[((size_t)b * DDIM + gj) * NTOK + gi] = acc[ii][jj][r];
            }
        }
}

extern "C" void kernel_launch(void* const* d_in, const int* in_sizes, int n_in,
                              void* d_out, int out_size, void* d_ws, size_t ws_size,
                              hipStream_t stream) {
    const float* x    = (const float*)d_in[0];   // (64,512,25,25) f32
    const float* wqkv = (const float*)d_in[1];   // (512,1536) f32
    const float* wout = (const float*)d_in[2];   // (512,512) f32
    const float* rpb  = (const float*)d_in[3];   // (2401,8) f32
    const int*   rpi  = (const int*)d_in[4];     // (625,625) int32
    float* out = (float*)d_out;

    char* ws = (char*)d_ws;
    size_t off = 0;
    auto alloc = [&](size_t nbytes) -> void* {
        void* p = ws + off;
        off += (nbytes + 255) & ~(size_t)255;
        return p;
    };
    u16* tokens   = (u16*)alloc((size_t)NB * NTOKP * DDIM * 2);    // 42 MB (reused as attnout)
    u16* qk       = (u16*)alloc((size_t)NB * NTOKP * 1024 * 2);    // 84 MB
    u16* vT       = (u16*)alloc((size_t)NB * NH * DH * NTOKP * 2); // 42 MB
    u16* wqkvT    = (u16*)alloc((size_t)1536 * DDIM * 2);
    u16* woutT    = (u16*)alloc((size_t)DDIM * DDIM * 2);
    float* biasCf = (float*)alloc((size_t)NH * 100 * 4096 * 4);    // 13.1 MB, C-layout f32
    u16* attnout  = tokens;  // tokens is dead after k_qkv; pad rows stay zero

    k_transpose_x<<<dim3(10, 8, NB), 256, 0, stream>>>(x, tokens);
    k_transpose_w<<<dim3(1536 / 64, DDIM / 64), 256, 0, stream>>>(wqkv, wqkvT, DDIM, 1536);
    k_transpose_w<<<dim3(DDIM / 64, DDIM / 64), 256, 0, stream>>>(wout, woutT, DDIM, DDIM);
    k_bias<<<dim3(800), 256, 0, stream>>>(rpi, rpb, biasCf);
    k_qkv<<<dim3(3840), 256, 0, stream>>>(tokens, wqkvT, qk, vT);
    k_attn<<<dim3(5120), 256, 0, stream>>>(qk, vT, biasCf, attnout);
    k_out<<<dim3(1280), 256, 0, stream>>>(attnout, woutT, out);
}